// Round 5
// baseline (458.855 us; speedup 1.0000x reference)
//
#include <hip/hip_runtime.h>
#include <math.h>

#define NROWS 65536
#define LLEN  1024
#define RBLOCKS (NROWS / 8)     // 8192 blocks: 4 waves/block x 2 rows/wave
#define FBLOCKS 256             // fold kernel blocks

// Per-row compute on register-resident data. f[p] holds elements
// {p*256 + 4*lane .. +3}. Gaussian window evaluated only for passes within
// +-75 samples of tpos (expf underflows to exactly 0.0f outside -> bit-exact).
__device__ __forceinline__ void row_compute(const float4* f, int lane, float tpos,
                                            float& d2s, float& mx,
                                            float& wsum, float& wesum) {
    d2s = 0.0f; mx = -INFINITY; wsum = 0.0f; wesum = 0.0f;
#pragma unroll
    for (int p = 0; p < 4; ++p) {
        const float x0 = f[p].x, x1 = f[p].y, x2 = f[p].z, x3 = f[p].w;

        float left  = __shfl_up(x3, 1, 64);
        float right = __shfl_down(x0, 1, 64);
        const float prevTail = __shfl((p > 0) ? f[p - 1].w : x0, 63, 64);
        const float nextHead = __shfl((p < 3) ? f[p + 1].x : x3, 0, 64);
        if (lane == 0)  left  = (p > 0) ? prevTail : x0;   // p==0: w1 - w0
        if (lane == 63) right = (p < 3) ? nextHead : x2;   // p==3: w[-2] - w[-1]

        const float d2a = x1 - 2.0f * x0 + left;
        const float d2b = x2 - 2.0f * x1 + x0;
        const float d2c = x3 - 2.0f * x2 + x1;
        const float d2d = right - 2.0f * x3 + x2;
        d2s += d2a * d2a + d2b * d2b + d2c * d2c + d2d * d2d;

        mx = fmaxf(fmaxf(mx, fmaxf(x0, x1)), fmaxf(x2, x3));

        const float pstart = (float)(p * 256);
        if (tpos > pstart - 75.0f && tpos < pstart + 330.0f) {
            const float e0 = pstart + (float)(4 * lane);
#pragma unroll
            for (int j = 0; j < 4; ++j) {
                const float c = (j == 0) ? x0 : (j == 1) ? x1 : (j == 2) ? x2 : x3;
                const float dt = (e0 + (float)j - tpos) * 0.2f;   // sigma = 5
                const float g = __expf(-0.5f * dt * dt);
                wsum  += g;
                wesum += c * c * g;
            }
        }
    }
}

// ---------------- kernel A: waveform pass + per-row CE/argmax ----------------
// 4 waves/block, 2 consecutive rows per wave. Lanes 0-1 additionally handle
// their rows' logits: nll (masked), valid count, argmax->isdef. isdef is
// packed into the sign bit of eraw (eraw > 0 almost surely; -0.0 keeps flag).
__global__ __launch_bounds__(256) void row_kernel(const float* __restrict__ wf,
                                                  const float* __restrict__ logits,
                                                  const float* __restrict__ depth,
                                                  const int* __restrict__ labels,
                                                  float* __restrict__ eraw,
                                                  float* __restrict__ d2_part,
                                                  float* __restrict__ mx_part,
                                                  float* __restrict__ nll_part,
                                                  float* __restrict__ nv_part,
                                                  unsigned int* __restrict__ counter) {
    __shared__ float s_d2[4], s_mx[4], s_nll[4], s_nv[4];
    const int wave = threadIdx.x >> 6;
    const int lane = threadIdx.x & 63;
    const int r0 = (blockIdx.x * 4 + wave) * 2;

    if (blockIdx.x == 0 && threadIdx.x == 0) *counter = 0u;  // for kernel B

    const float4* srcA = (const float4*)(wf + (size_t)r0 * LLEN);
    const float4* srcB = srcA + (LLEN / 4);
    float4 fA[4], fB[4];
#pragma unroll
    for (int p = 0; p < 4; ++p) fA[p] = srcA[p * 64 + lane];
#pragma unroll
    for (int p = 0; p < 4; ++p) fB[p] = srcB[p * 64 + lane];
    const float2 dep = *(const float2*)(depth + r0);

    // lanes 0-1: CE + argmax for rows r0, r0+1
    float nll = 0.0f, nv = 0.0f;
    bool isdef = false;
    if (lane < 2) {
        const int r = r0 + lane;
        const float4 lg = ((const float4*)logits)[r];
        const float m = fmaxf(fmaxf(lg.x, lg.y), fmaxf(lg.z, lg.w));
        const float lse = m + logf(__expf(lg.x - m) + __expf(lg.y - m) +
                                   __expf(lg.z - m) + __expf(lg.w - m));
        const int lab = labels[r];
        const bool valid = (lab != -1);
        const int sl = valid ? lab : 0;
        const float lv = (sl == 0) ? lg.x : (sl == 1) ? lg.y : (sl == 2) ? lg.z : lg.w;
        nll = valid ? (lse - lv) : 0.0f;
        nv  = valid ? 1.0f : 0.0f;
        int pc = 0; float bv = lg.x;
        if (lg.y > bv) { bv = lg.y; pc = 1; }
        if (lg.z > bv) { bv = lg.z; pc = 2; }
        if (lg.w > bv) { bv = lg.w; pc = 3; }
        isdef = (pc == 2) || (pc == 3);
    }

    float d2sA, mxA, wsA, weA, d2sB, mxB, wsB, weB;
    row_compute(fA, lane, dep.x * 10.0f, d2sA, mxA, wsA, weA);
    row_compute(fB, lane, dep.y * 10.0f, d2sB, mxB, wsB, weB);

#pragma unroll
    for (int off = 32; off > 0; off >>= 1) {
        wsA += __shfl_down(wsA, off, 64);
        weA += __shfl_down(weA, off, 64);
        wsB += __shfl_down(wsB, off, 64);
        weB += __shfl_down(weB, off, 64);
    }
    float d2s = d2sA + d2sB;
    float mx  = fmaxf(mxA, mxB);
#pragma unroll
    for (int off = 32; off > 0; off >>= 1) {
        d2s += __shfl_down(d2s, off, 64);
        mx = fmaxf(mx, __shfl_down(mx, off, 64));
    }
    // bring row B's window sums to lane 1; fold nll/nv of lanes 0,1 to lane 0
    const float wsB0 = __shfl(wsB, 0, 64);
    const float weB0 = __shfl(weB, 0, 64);
    const float nll01 = nll + __shfl_down(nll, 1, 64);
    const float nv01  = nv  + __shfl_down(nv, 1, 64);

    if (lane < 2) {
        const float e = (lane == 0) ? (weA / wsA) : (weB0 / wsB0);
        const unsigned int bits = __float_as_uint(e) | (isdef ? 0x80000000u : 0u);
        eraw[r0 + lane] = __uint_as_float(bits);
    }
    if (lane == 0) {
        s_d2[wave] = d2s;  s_mx[wave] = mx;
        s_nll[wave] = nll01;  s_nv[wave] = nv01;
    }
    __syncthreads();
    if (threadIdx.x == 0) {
        d2_part[blockIdx.x]  = s_d2[0] + s_d2[1] + s_d2[2] + s_d2[3];
        mx_part[blockIdx.x]  = fmaxf(fmaxf(s_mx[0], s_mx[1]), fmaxf(s_mx[2], s_mx[3]));
        nll_part[blockIdx.x] = s_nll[0] + s_nll[1] + s_nll[2] + s_nll[3];
        nv_part[blockIdx.x]  = s_nv[0] + s_nv[1] + s_nv[2] + s_nv[3];
    }
}

// ---------------- kernel B: fold partials + penalty + final (last-block) ----------------
__global__ __launch_bounds__(256) void fold_kernel(const float* __restrict__ d2_part,
                                                   const float* __restrict__ mx_part,
                                                   const float* __restrict__ nll_part,
                                                   const float* __restrict__ nv_part,
                                                   const float* __restrict__ eraw,
                                                   double* __restrict__ d2_p2,
                                                   float* __restrict__ mx_p2,
                                                   double* __restrict__ nll_p2,
                                                   float* __restrict__ nv_p2,
                                                   unsigned int* __restrict__ counter,
                                                   float* __restrict__ out) {
    const int wave = threadIdx.x >> 6;
    const int lane = threadIdx.x & 63;

    // phase 1: each block folds its 32-entry slice of the 8192 partials
    {
        const int base = blockIdx.x * 32;
        double d2 = 0.0, nl = 0.0;
        float mx = -INFINITY, nv = 0.0f;
        if (threadIdx.x < 32) {
            const int i = base + threadIdx.x;
            d2 = (double)d2_part[i];
            nl = (double)nll_part[i];
            mx = mx_part[i];
            nv = nv_part[i];
        }
        if (wave == 0) {
#pragma unroll
            for (int off = 16; off > 0; off >>= 1) {
                d2 += __shfl_down(d2, off, 64);
                nl += __shfl_down(nl, off, 64);
                nv += __shfl_down(nv, off, 64);
                mx = fmaxf(mx, __shfl_down(mx, off, 64));
            }
            if (lane == 0) {
                d2_p2[blockIdx.x] = d2;
                nll_p2[blockIdx.x] = nl;
                mx_p2[blockIdx.x] = mx;
                nv_p2[blockIdx.x] = nv;
            }
        }
    }
    __threadfence();
    __shared__ bool amLast;
    if (threadIdx.x == 0)
        amLast = (atomicAdd(counter, 1u) == FBLOCKS - 1);
    __syncthreads();
    if (!amLast) return;
    __threadfence();

    // phase 2 (last block only): fold 256 second-level partials
    __shared__ double sh_d2[4], sh_nll[4];
    __shared__ float sh_mx[4], sh_nv[4];
    __shared__ float sh_gmax;
    __shared__ double sh_base[3];   // cls, wave loss, nll placeholder
    {
        double d2 = d2_p2[threadIdx.x];
        double nl = nll_p2[threadIdx.x];
        float mx = mx_p2[threadIdx.x];
        float nv = nv_p2[threadIdx.x];
#pragma unroll
        for (int off = 32; off > 0; off >>= 1) {
            d2 += __shfl_down(d2, off, 64);
            nl += __shfl_down(nl, off, 64);
            nv += __shfl_down(nv, off, 64);
            mx = fmaxf(mx, __shfl_down(mx, off, 64));
        }
        if (lane == 0) { sh_d2[wave] = d2; sh_nll[wave] = nl; sh_mx[wave] = mx; sh_nv[wave] = nv; }
    }
    __syncthreads();
    if (threadIdx.x == 0) {
        const double d2_sum = sh_d2[0] + sh_d2[1] + sh_d2[2] + sh_d2[3];
        const double nll_sum = sh_nll[0] + sh_nll[1] + sh_nll[2] + sh_nll[3];
        const float nv_sum = sh_nv[0] + sh_nv[1] + sh_nv[2] + sh_nv[3];
        sh_gmax = fmaxf(fmaxf(sh_mx[0], sh_mx[1]), fmaxf(sh_mx[2], sh_mx[3]));
        sh_base[0] = (nv_sum > 0.0f) ? nll_sum / (double)nv_sum : 0.0;
        sh_base[1] = d2_sum * (9900.0 * 9900.0) / ((double)NROWS * (double)LLEN);
    }
    __syncthreads();
    const float inv20g = 1.0f / (20.0f * sh_gmax);

    // phase 3: penalty sweep over 65536 encoded eraw values
    float pen = 0.0f;
    for (int r = threadIdx.x; r < NROWS; r += 256) {
        const float v = eraw[r];
        const bool isdef = signbit(v);
        const float E = fabsf(v) * inv20g;
        if (isdef) pen += (E < 0.1f) ? (0.1f - E) * (0.1f - E) : 0.0f;
        else       pen += (E > 0.5f) ? (E - 0.5f) * (E - 0.5f) : 0.0f;
    }
    __shared__ double sh_pen[4];
    double pend = (double)pen;
#pragma unroll
    for (int off = 32; off > 0; off >>= 1) pend += __shfl_down(pend, off, 64);
    if (lane == 0) sh_pen[wave] = pend;
    __syncthreads();
    if (threadIdx.x == 0) {
        const double phys = (sh_pen[0] + sh_pen[1] + sh_pen[2] + sh_pen[3]) / (double)NROWS;
        const double cls = sh_base[0];
        const double wave_l = sh_base[1];
        out[0] = (float)(cls + 0.1 * wave_l + 0.1 * phys);
        out[1] = (float)cls;
        out[2] = (float)wave_l;
        out[3] = (float)phys;
    }
}

extern "C" void kernel_launch(void* const* d_in, const int* in_sizes, int n_in,
                              void* d_out, int out_size, void* d_ws, size_t ws_size,
                              hipStream_t stream) {
    const float* wf     = (const float*)d_in[0];
    const float* logits = (const float*)d_in[1];
    const float* depth  = (const float*)d_in[2];
    const int*   labels = (const int*)d_in[3];
    float* out = (float*)d_out;

    char* ws = (char*)d_ws;
    unsigned int* counter = (unsigned int*)ws;        ws += 256;
    float* eraw     = (float*)ws;                     ws += NROWS * sizeof(float);
    float* d2_part  = (float*)ws;                     ws += RBLOCKS * sizeof(float);
    float* mx_part  = (float*)ws;                     ws += RBLOCKS * sizeof(float);
    float* nll_part = (float*)ws;                     ws += RBLOCKS * sizeof(float);
    float* nv_part  = (float*)ws;                     ws += RBLOCKS * sizeof(float);
    double* d2_p2   = (double*)ws;                    ws += FBLOCKS * sizeof(double);
    double* nll_p2  = (double*)ws;                    ws += FBLOCKS * sizeof(double);
    float* mx_p2    = (float*)ws;                     ws += FBLOCKS * sizeof(float);
    float* nv_p2    = (float*)ws;

    row_kernel<<<RBLOCKS, 256, 0, stream>>>(wf, logits, depth, labels, eraw,
                                            d2_part, mx_part, nll_part, nv_part, counter);
    fold_kernel<<<FBLOCKS, 256, 0, stream>>>(d2_part, mx_part, nll_part, nv_part, eraw,
                                             d2_p2, mx_p2, nll_p2, nv_p2, counter, out);
}

// Round 6
// 371.804 us; speedup vs baseline: 1.2341x; 1.2341x over previous
//
#include <hip/hip_runtime.h>
#include <math.h>

#define NROWS 65536
#define LLEN  1024
#define RBLOCKS (NROWS / 8)     // 8192 blocks: 4 waves/block x 2 rows/wave
#define CBLOCKS (NROWS / 256)   // 256 cls-kernel blocks

struct Acc {
    double d2_sum;
    float  gmax;
};

// Per-row compute on register-resident data. f[p] holds elements
// {p*256 + 4*lane .. +3}. Gaussian window evaluated only for passes within
// +-75 samples of tpos (expf underflows to exactly 0.0f outside -> bit-exact).
__device__ __forceinline__ void row_compute(const float4* f, int lane, float tpos,
                                            float& d2s, float& mx,
                                            float& wsum, float& wesum) {
    d2s = 0.0f; mx = -INFINITY; wsum = 0.0f; wesum = 0.0f;
#pragma unroll
    for (int p = 0; p < 4; ++p) {
        const float x0 = f[p].x, x1 = f[p].y, x2 = f[p].z, x3 = f[p].w;

        float left  = __shfl_up(x3, 1, 64);
        float right = __shfl_down(x0, 1, 64);
        const float prevTail = __shfl((p > 0) ? f[p - 1].w : x0, 63, 64);
        const float nextHead = __shfl((p < 3) ? f[p + 1].x : x3, 0, 64);
        if (lane == 0)  left  = (p > 0) ? prevTail : x0;   // p==0: w1 - w0
        if (lane == 63) right = (p < 3) ? nextHead : x2;   // p==3: w[-2] - w[-1]

        const float d2a = x1 - 2.0f * x0 + left;
        const float d2b = x2 - 2.0f * x1 + x0;
        const float d2c = x3 - 2.0f * x2 + x1;
        const float d2d = right - 2.0f * x3 + x2;
        d2s += d2a * d2a + d2b * d2b + d2c * d2c + d2d * d2d;

        mx = fmaxf(fmaxf(mx, fmaxf(x0, x1)), fmaxf(x2, x3));

        const float pstart = (float)(p * 256);
        if (tpos > pstart - 75.0f && tpos < pstart + 330.0f) {
            const float e0 = pstart + (float)(4 * lane);
#pragma unroll
            for (int j = 0; j < 4; ++j) {
                const float c = (j == 0) ? x0 : (j == 1) ? x1 : (j == 2) ? x2 : x3;
                const float dt = (e0 + (float)j - tpos) * 0.2f;   // sigma = 5
                const float g = __expf(-0.5f * dt * dt);
                wsum  += g;
                wesum += c * c * g;
            }
        }
    }
}

// ---------------- kernel 1: waveform pass ----------------
__global__ __launch_bounds__(256) void row_kernel(const float* __restrict__ wf,
                                                  const float* __restrict__ depth,
                                                  float* __restrict__ eraw,
                                                  float* __restrict__ d2_part,
                                                  float* __restrict__ mx_part) {
    __shared__ float s_d2[4], s_mx[4];
    const int wave = threadIdx.x >> 6;
    const int lane = threadIdx.x & 63;
    const int r0 = (blockIdx.x * 4 + wave) * 2;

    const float4* srcA = (const float4*)(wf + (size_t)r0 * LLEN);
    const float4* srcB = srcA + (LLEN / 4);
    float4 fA[4], fB[4];
#pragma unroll
    for (int p = 0; p < 4; ++p) fA[p] = srcA[p * 64 + lane];
#pragma unroll
    for (int p = 0; p < 4; ++p) fB[p] = srcB[p * 64 + lane];
    const float2 dep = *(const float2*)(depth + r0);

    float d2sA, mxA, wsA, weA, d2sB, mxB, wsB, weB;
    row_compute(fA, lane, dep.x * 10.0f, d2sA, mxA, wsA, weA);
    row_compute(fB, lane, dep.y * 10.0f, d2sB, mxB, wsB, weB);

#pragma unroll
    for (int off = 32; off > 0; off >>= 1) {
        wsA += __shfl_down(wsA, off, 64);
        weA += __shfl_down(weA, off, 64);
        wsB += __shfl_down(wsB, off, 64);
        weB += __shfl_down(weB, off, 64);
    }
    float d2s = d2sA + d2sB;
    float mx  = fmaxf(mxA, mxB);
#pragma unroll
    for (int off = 32; off > 0; off >>= 1) {
        d2s += __shfl_down(d2s, off, 64);
        mx = fmaxf(mx, __shfl_down(mx, off, 64));
    }

    if (lane == 0) {
        eraw[r0]     = weA / wsA;
        eraw[r0 + 1] = weB / wsB;
        s_d2[wave] = d2s;
        s_mx[wave] = mx;
    }
    __syncthreads();
    if (threadIdx.x == 0) {
        d2_part[blockIdx.x] = s_d2[0] + s_d2[1] + s_d2[2] + s_d2[3];
        mx_part[blockIdx.x] = fmaxf(fmaxf(s_mx[0], s_mx[1]), fmaxf(s_mx[2], s_mx[3]));
    }
}

// ---------------- kernel 2: fold 8192 partials -> Acc ----------------
__global__ __launch_bounds__(256) void reduce_kernel(const float* __restrict__ d2_part,
                                                     const float* __restrict__ mx_part,
                                                     Acc* __restrict__ acc) {
    __shared__ double s_d2[4];
    __shared__ float  s_mx[4];
    const int wave = threadIdx.x >> 6;
    const int lane = threadIdx.x & 63;

    double d2 = 0.0;
    float mx = -INFINITY;
    for (int i = threadIdx.x; i < RBLOCKS; i += 256) {
        d2 += (double)d2_part[i];
        mx = fmaxf(mx, mx_part[i]);
    }
#pragma unroll
    for (int off = 32; off > 0; off >>= 1) {
        d2 += __shfl_down(d2, off, 64);
        mx = fmaxf(mx, __shfl_down(mx, off, 64));
    }
    if (lane == 0) { s_d2[wave] = d2; s_mx[wave] = mx; }
    __syncthreads();
    if (threadIdx.x == 0) {
        acc->d2_sum = s_d2[0] + s_d2[1] + s_d2[2] + s_d2[3];
        acc->gmax   = fmaxf(fmaxf(s_mx[0], s_mx[1]), fmaxf(s_mx[2], s_mx[3]));
    }
}

// ---------------- kernel 3: CE + argmax + penalty ----------------
__global__ __launch_bounds__(256) void cls_kernel(const float* __restrict__ logits,
                                                  const int* __restrict__ labels,
                                                  const float* __restrict__ eraw,
                                                  const Acc* __restrict__ acc,
                                                  float* __restrict__ nll_part,
                                                  float* __restrict__ pen_part,
                                                  int* __restrict__ nv_part) {
    __shared__ float s_nll[4], s_pen[4];
    __shared__ int   s_nv[4];
    const int wave = threadIdx.x >> 6;
    const int lane = threadIdx.x & 63;
    const int r = blockIdx.x * 256 + threadIdx.x;

    const float4 lg = ((const float4*)logits)[r];
    const float m = fmaxf(fmaxf(lg.x, lg.y), fmaxf(lg.z, lg.w));
    const float lse = m + logf(__expf(lg.x - m) + __expf(lg.y - m) +
                               __expf(lg.z - m) + __expf(lg.w - m));

    const int lab = labels[r];
    const bool valid = (lab != -1);
    const int sl = valid ? lab : 0;
    const float lv = (sl == 0) ? lg.x : (sl == 1) ? lg.y : (sl == 2) ? lg.z : lg.w;
    float nll = valid ? (lse - lv) : 0.0f;

    int pc = 0; float bv = lg.x;
    if (lg.y > bv) { bv = lg.y; pc = 1; }
    if (lg.z > bv) { bv = lg.z; pc = 2; }
    if (lg.w > bv) { bv = lg.w; pc = 3; }

    const float E = eraw[r] / (20.0f * acc->gmax);
    const bool isdef = (pc == 2) || (pc == 3);
    float pen;
    if (isdef) pen = (E < 0.1f) ? (0.1f - E) * (0.1f - E) : 0.0f;
    else       pen = (E > 0.5f) ? (E - 0.5f) * (E - 0.5f) : 0.0f;

    const unsigned long long bal = __ballot(valid);
#pragma unroll
    for (int off = 32; off > 0; off >>= 1) {
        nll += __shfl_down(nll, off, 64);
        pen += __shfl_down(pen, off, 64);
    }
    if (lane == 0) { s_nll[wave] = nll; s_pen[wave] = pen; s_nv[wave] = __popcll(bal); }
    __syncthreads();
    if (threadIdx.x == 0) {
        nll_part[blockIdx.x] = s_nll[0] + s_nll[1] + s_nll[2] + s_nll[3];
        pen_part[blockIdx.x] = s_pen[0] + s_pen[1] + s_pen[2] + s_pen[3];
        nv_part[blockIdx.x]  = s_nv[0] + s_nv[1] + s_nv[2] + s_nv[3];
    }
}

// ---------------- kernel 4: fold 256 cls partials, emit 4 scalars ----------------
__global__ __launch_bounds__(256) void final_kernel(const float* __restrict__ nll_part,
                                                    const float* __restrict__ pen_part,
                                                    const int* __restrict__ nv_part,
                                                    const Acc* __restrict__ acc,
                                                    float* __restrict__ out) {
    __shared__ double s_nll[4], s_pen[4];
    __shared__ int    s_nv[4];
    const int wave = threadIdx.x >> 6;
    const int lane = threadIdx.x & 63;

    double nll = (double)nll_part[threadIdx.x];
    double pen = (double)pen_part[threadIdx.x];
    int nv = nv_part[threadIdx.x];
#pragma unroll
    for (int off = 32; off > 0; off >>= 1) {
        nll += __shfl_down(nll, off, 64);
        pen += __shfl_down(pen, off, 64);
        nv  += __shfl_down(nv,  off, 64);
    }
    if (lane == 0) { s_nll[wave] = nll; s_pen[wave] = pen; s_nv[wave] = nv; }
    __syncthreads();
    if (threadIdx.x == 0) {
        const double nll_s = s_nll[0] + s_nll[1] + s_nll[2] + s_nll[3];
        const double pen_s = s_pen[0] + s_pen[1] + s_pen[2] + s_pen[3];
        const int    nv_s  = s_nv[0] + s_nv[1] + s_nv[2] + s_nv[3];
        const double cls  = (nv_s > 0) ? nll_s / (double)nv_s : 0.0;
        const double wave_l = acc->d2_sum * (9900.0 * 9900.0) / ((double)NROWS * (double)LLEN);
        const double phys = pen_s / (double)NROWS;
        out[0] = (float)(cls + 0.1 * wave_l + 0.1 * phys);
        out[1] = (float)cls;
        out[2] = (float)wave_l;
        out[3] = (float)phys;
    }
}

extern "C" void kernel_launch(void* const* d_in, const int* in_sizes, int n_in,
                              void* d_out, int out_size, void* d_ws, size_t ws_size,
                              hipStream_t stream) {
    const float* wf     = (const float*)d_in[0];
    const float* logits = (const float*)d_in[1];
    const float* depth  = (const float*)d_in[2];
    const int*   labels = (const int*)d_in[3];
    float* out = (float*)d_out;

    char* ws = (char*)d_ws;
    Acc*   acc      = (Acc*)ws;                       ws += 256;
    float* eraw     = (float*)ws;                     ws += NROWS * sizeof(float);
    float* d2_part  = (float*)ws;                     ws += RBLOCKS * sizeof(float);
    float* mx_part  = (float*)ws;                     ws += RBLOCKS * sizeof(float);
    float* nll_part = (float*)ws;                     ws += CBLOCKS * sizeof(float);
    float* pen_part = (float*)ws;                     ws += CBLOCKS * sizeof(float);
    int*   nv_part  = (int*)ws;

    row_kernel<<<RBLOCKS, 256, 0, stream>>>(wf, depth, eraw, d2_part, mx_part);
    reduce_kernel<<<1, 256, 0, stream>>>(d2_part, mx_part, acc);
    cls_kernel<<<CBLOCKS, 256, 0, stream>>>(logits, labels, eraw, acc, nll_part, pen_part, nv_part);
    final_kernel<<<1, 256, 0, stream>>>(nll_part, pen_part, nv_part, acc, out);
}